// Round 1
// baseline (761.999 us; speedup 1.0000x reference)
//
#include <hip/hip_runtime.h>
#include <stdint.h>

// AttentionBlock: GroupNorm(32) -> QKV 1x1 conv -> full 4096x4096 single-head
// attention per batch -> out projection + residual.  B=4, HW=4096, C=512.
// All GEMMs: bf16 MFMA 16x16x32, 128x128 tiles, NT form (both operands
// K-contiguous), global_load_lds width-16 staging (m97 ladder structure).

typedef __attribute__((ext_vector_type(8))) short bf16x8;
typedef __attribute__((ext_vector_type(4))) float f32x4;

__device__ __forceinline__ unsigned short f2bf(float f) {
  unsigned int x = __float_as_uint(f);
  x += 0x7fffu + ((x >> 16) & 1u);       // round-to-nearest-even
  return (unsigned short)(x >> 16);
}

__device__ __forceinline__ void gl_lds16(const void* g, void* l) {
  // async global->LDS, 16B per lane; LDS dest = wave-uniform base + lane*16
  __builtin_amdgcn_global_load_lds(
      (__attribute__((address_space(1))) unsigned char*)g,
      (__attribute__((address_space(3))) unsigned char*)l, 16, 0, 0);
}

// ---------- prep: weights -> [N][K] bf16 transposed, pack qkv bias ----------
__global__ void prep_kernel(const float* __restrict__ wq, const float* __restrict__ wk,
                            const float* __restrict__ wv, const float* __restrict__ wo,
                            const float* __restrict__ bq, const float* __restrict__ bk,
                            const float* __restrict__ bv,
                            unsigned short* __restrict__ wqkvT,
                            unsigned short* __restrict__ woT,
                            float* __restrict__ bias) {
  long id = (long)blockIdx.x * 256 + threadIdx.x;
  if (id < 786432) {                       // wqkvT[n][k], n in [0,1536)
    long n = id >> 9, k = id & 511;
    const float* w = (n < 512) ? wq : (n < 1024 ? wk : wv);
    wqkvT[id] = f2bf(w[k * 512 + (n & 511)]);
  } else if (id < 786432 + 262144) {       // woT[n][k]
    long j = id - 786432, n = j >> 9, k = j & 511;
    woT[j] = f2bf(wo[k * 512 + n]);
  } else if (id < 786432 + 262144 + 1536) {
    long j = id - 786432 - 262144;
    bias[j] = (j < 512) ? bq[j] : (j < 1024 ? bk[j - 512] : bv[j - 1024]);
  }
}

// ---------- GroupNorm: one block per (batch, group); 4096 px * 16 ch ----------
__global__ __launch_bounds__(256) void groupnorm_kernel(
    const float* __restrict__ x, const float* __restrict__ gamma,
    const float* __restrict__ beta, unsigned short* __restrict__ xn) {
  const int b = blockIdx.x >> 5, g = blockIdx.x & 31;
  const int tid = threadIdx.x;
  const long base = ((long)b * 4096) * 512 + g * 16;
  const int c4 = tid & 3;                  // which float4 of the group's 16 ch

  float s = 0.f, s2 = 0.f;
  for (int i = tid; i < 16384; i += 256) { // 4096 px * 4 float4
    int pp = i >> 2;
    float4 v = *(const float4*)(x + base + (long)pp * 512 + c4 * 4);
    s += v.x + v.y + v.z + v.w;
    s2 += v.x * v.x + v.y * v.y + v.z * v.z + v.w * v.w;
  }
  for (int o = 32; o; o >>= 1) { s += __shfl_xor(s, o); s2 += __shfl_xor(s2, o); }
  __shared__ float red[2][4];
  int wave = tid >> 6, lane = tid & 63;
  if (lane == 0) { red[0][wave] = s; red[1][wave] = s2; }
  __syncthreads();
  float ts = red[0][0] + red[0][1] + red[0][2] + red[0][3];
  float ts2 = red[1][0] + red[1][1] + red[1][2] + red[1][3];
  float mean = ts * (1.f / 65536.f);
  float var = ts2 * (1.f / 65536.f) - mean * mean;
  float rinv = rsqrtf(var + 1e-6f);

  float4 gm = *(const float4*)(gamma + g * 16 + c4 * 4);
  float4 bt = *(const float4*)(beta + g * 16 + c4 * 4);
  for (int i = tid; i < 16384; i += 256) {
    int pp = i >> 2;
    float4 v = *(const float4*)(x + base + (long)pp * 512 + c4 * 4);
    ushort4 o;
    o.x = f2bf((v.x - mean) * rinv * gm.x + bt.x);
    o.y = f2bf((v.y - mean) * rinv * gm.y + bt.y);
    o.z = f2bf((v.z - mean) * rinv * gm.z + bt.z);
    o.w = f2bf((v.w - mean) * rinv * gm.w + bt.w);
    *(ushort4*)(xn + base + (long)pp * 512 + c4 * 4) = o;
  }
}

// ---------- generic 128x128 bf16 NT GEMM with templated epilogue ----------
// C[m,n] = sum_k A[m,k] * B[n,k]   (A: [M][lda], B: [N][ldb], bf16)
struct EpiArgs {
  float* out_f32;
  unsigned short* out_bf16;
  unsigned short *q, *k, *vT;
  const float* bias;
  const float* resid;
  float scale;
};

template <int EPI>
__global__ __launch_bounds__(256) void gemm_nt(
    const unsigned short* __restrict__ A, long lda,
    const unsigned short* __restrict__ B, long ldb,
    int K, EpiArgs e) {
  __shared__ unsigned short As[128 * 64];  // [row][k] 16KB
  __shared__ unsigned short Bs[128 * 64];
  const int tid = threadIdx.x;
  const int wave = tid >> 6, lane = tid & 63;
  const long tm = (long)blockIdx.x * 128;
  const long tn = (long)blockIdx.y * 128;

  f32x4 acc[4][4] = {};

  const int srow = lane >> 3;              // row within 8-row staging chunk
  const int soff = (lane & 7) * 16;        // byte offset within 128B row
  const int wm = (wave >> 1) * 64, wn = (wave & 1) * 64;
  const int lrow = lane & 15, lko = (lane >> 4) * 8;

  for (int k0 = 0; k0 < K; k0 += 64) {
    __syncthreads();                       // protect LDS from prev readers
    for (int i = 0; i < 4; ++i) {
      int chunk = wave * 4 + i;            // 1KB chunk = 8 rows x 128B
      int row = chunk * 8 + srow;
      gl_lds16((const char*)(A + (tm + row) * lda + k0) + soff, (char*)As + chunk * 1024);
      gl_lds16((const char*)(B + (tn + row) * ldb + k0) + soff, (char*)Bs + chunk * 1024);
    }
    __syncthreads();                       // drains vmcnt(0) for load_lds
#pragma unroll
    for (int ks = 0; ks < 2; ++ks) {
      bf16x8 af[4], bf[4];
#pragma unroll
      for (int t = 0; t < 4; ++t) {
        af[t] = *(const bf16x8*)&As[(wm + t * 16 + lrow) * 64 + ks * 32 + lko];
        bf[t] = *(const bf16x8*)&Bs[(wn + t * 16 + lrow) * 64 + ks * 32 + lko];
      }
#pragma unroll
      for (int mt = 0; mt < 4; ++mt)
#pragma unroll
        for (int nt = 0; nt < 4; ++nt)
          acc[mt][nt] = __builtin_amdgcn_mfma_f32_16x16x32_bf16(af[mt], bf[nt], acc[mt][nt], 0, 0, 0);
    }
  }

  // C/D layout (verified m89/m91): col = lane&15, row = (lane>>4)*4 + reg
  const int lcol = lane & 15, lrb = (lane >> 4) * 4;
#pragma unroll
  for (int mt = 0; mt < 4; ++mt)
#pragma unroll
    for (int nt = 0; nt < 4; ++nt)
#pragma unroll
      for (int r = 0; r < 4; ++r) {
        long m = tm + wm + mt * 16 + lrb + r;
        long n = tn + wn + nt * 16 + lcol;
        float v = acc[mt][nt][r];
        if (EPI == 0) {                    // QKV: n<512 q, <1024 k, else v^T
          v += e.bias[n];
          unsigned short h = f2bf(v);
          if (n < 512)            e.q[m * 512 + n] = h;
          else if (n < 1024)      e.k[m * 512 + (n - 512)] = h;
          else                    e.vT[((m >> 12) * 512 + (n - 1024)) * 4096 + (m & 4095)] = h;
        } else if (EPI == 1) {             // scores * c^-0.5, fp32
          e.out_f32[m * 4096 + n] = v * e.scale;
        } else if (EPI == 2) {             // PV -> bf16 attn_out
          e.out_bf16[m * 512 + n] = f2bf(v);
        } else {                           // proj + bias + residual -> d_out
          e.out_f32[m * 512 + n] = v + e.bias[n] + e.resid[m * 512 + n];
        }
      }
}

// ---------- row softmax, writes bf16 probs in-place into fp32 score rows ----
__global__ __launch_bounds__(256) void softmax_kernel(float* __restrict__ scores) {
  const long r = blockIdx.x;
  const float* row = scores + r * 4096;
  const int tid = threadIdx.x;
  float vals[16];
  float mx = -1e30f;
#pragma unroll
  for (int j = 0; j < 16; ++j) {
    vals[j] = row[tid + j * 256];
    mx = fmaxf(mx, vals[j]);
  }
  for (int o = 32; o; o >>= 1) mx = fmaxf(mx, __shfl_xor(mx, o));
  __shared__ float redm[4], reds[4];
  int wave = tid >> 6, lane = tid & 63;
  if (lane == 0) redm[wave] = mx;
  __syncthreads();
  mx = fmaxf(fmaxf(redm[0], redm[1]), fmaxf(redm[2], redm[3]));
  float sum = 0.f;
#pragma unroll
  for (int j = 0; j < 16; ++j) {
    vals[j] = __expf(vals[j] - mx);
    sum += vals[j];
  }
  for (int o = 32; o; o >>= 1) sum += __shfl_xor(sum, o);
  if (lane == 0) reds[wave] = sum;
  __syncthreads();
  sum = reds[0] + reds[1] + reds[2] + reds[3];
  float inv = 1.f / sum;
  unsigned short* prow = (unsigned short*)scores + r * 8192;  // first half of row
#pragma unroll
  for (int j = 0; j < 16; ++j) prow[tid + j * 256] = f2bf(vals[j] * inv);
}

extern "C" void kernel_launch(void* const* d_in, const int* in_sizes, int n_in,
                              void* d_out, int out_size, void* d_ws, size_t ws_size,
                              hipStream_t stream) {
  const float* x     = (const float*)d_in[0];
  const float* gamma = (const float*)d_in[1];
  const float* beta  = (const float*)d_in[2];
  const float* wq    = (const float*)d_in[3];
  const float* bq    = (const float*)d_in[4];
  const float* wk    = (const float*)d_in[5];
  const float* bk    = (const float*)d_in[6];
  const float* wv    = (const float*)d_in[7];
  const float* bv    = (const float*)d_in[8];
  const float* wo    = (const float*)d_in[9];
  const float* bo    = (const float*)d_in[10];

  char* p = (char*)d_ws;
  auto take = [&](size_t bytes) { char* r = p; p += (bytes + 255) & ~(size_t)255; return r; };
  unsigned short* xn    = (unsigned short*)take(16384l * 512 * 2);
  unsigned short* q     = (unsigned short*)take(16384l * 512 * 2);
  unsigned short* kbuf  = (unsigned short*)take(16384l * 512 * 2);
  unsigned short* vT    = (unsigned short*)take(16384l * 512 * 2);  // [b][c][token]
  unsigned short* attn  = (unsigned short*)take(16384l * 512 * 2);
  unsigned short* wqkvT = (unsigned short*)take(1536l * 512 * 2);
  unsigned short* woT   = (unsigned short*)take(512l * 512 * 2);
  float* bias           = (float*)take(1536 * 4);
  float* scores         = (float*)take(4096l * 4096 * 4);           // reused per batch

  prep_kernel<<<4103, 256, 0, stream>>>(wq, wk, wv, wo, bq, bk, bv, wqkvT, woT, bias);
  groupnorm_kernel<<<128, 256, 0, stream>>>(x, gamma, beta, xn);

  EpiArgs e0 = {}; e0.q = q; e0.k = kbuf; e0.vT = vT; e0.bias = bias;
  gemm_nt<0><<<dim3(128, 12), 256, 0, stream>>>(xn, 512, wqkvT, 512, 512, e0);

  for (int b = 0; b < 4; ++b) {
    EpiArgs e1 = {}; e1.out_f32 = scores; e1.scale = 0.044194173824159216f;  // 512^-0.5
    gemm_nt<1><<<dim3(32, 32), 256, 0, stream>>>(q + (long)b * 4096 * 512, 512,
                                                 kbuf + (long)b * 4096 * 512, 512, 512, e1);
    softmax_kernel<<<4096, 256, 0, stream>>>(scores);
    EpiArgs e2 = {}; e2.out_bf16 = attn + (long)b * 4096 * 512;
    gemm_nt<2><<<dim3(32, 4), 256, 0, stream>>>((unsigned short*)scores, 8192,
                                                vT + (long)b * 512l * 4096, 4096, 4096, e2);
  }

  EpiArgs e3 = {}; e3.out_f32 = (float*)d_out; e3.bias = bo; e3.resid = x;
  gemm_nt<3><<<dim3(128, 4), 256, 0, stream>>>(attn, 512, woT, 512, 512, e3);
}

// Round 2
// 507.551 us; speedup vs baseline: 1.5013x; 1.5013x over previous
//
#include <hip/hip_runtime.h>
#include <stdint.h>

// AttentionBlock: GroupNorm(32) -> QKV -> full 4096x4096 attention per batch
// -> out projection + residual.  B=4, HW=4096, C=512.
// R1: batched+split-K PV, XOR-swizzled LDS staging (kills 16-way conflicts),
// coalesced 2-kernel GroupNorm, bf16 scores, LDS-transpose for vT.

typedef __attribute__((ext_vector_type(8))) short bf16x8;
typedef __attribute__((ext_vector_type(8))) unsigned short u16x8;
typedef __attribute__((ext_vector_type(4))) float f32x4;

#define SOFTMAX_SCALE 0.044194173824159216f  // 512^-0.5

__device__ __forceinline__ unsigned short f2bf(float f) {
  unsigned int x = __float_as_uint(f);
  x += 0x7fffu + ((x >> 16) & 1u);
  return (unsigned short)(x >> 16);
}
__device__ __forceinline__ float bf2f(unsigned short u) {
  return __uint_as_float((unsigned int)u << 16);
}

__device__ __forceinline__ void gl_lds16(const void* g, void* l) {
  __builtin_amdgcn_global_load_lds(
      (__attribute__((address_space(1))) unsigned char*)g,
      (__attribute__((address_space(3))) unsigned char*)l, 16, 0, 0);
}

// ---------------- shared 128x128 bf16 NT tile: C = A * B^T ----------------
// A,B rows K-contiguous. LDS 16B granules XOR-swizzled by (row&7) so the
// fragment reads (rows 128B apart = same bank) become 2-way (free).
__device__ __forceinline__ void gemm_tile(
    const unsigned short* __restrict__ A, long lda,
    const unsigned short* __restrict__ B, long ldb,
    int K, unsigned short* As, unsigned short* Bs, f32x4 acc[4][4]) {
  const int tid = threadIdx.x;
  const int wave = tid >> 6, lane = tid & 63;
  const int srow = lane >> 3;            // row within 8-row chunk
  const int soff = ((lane & 7) ^ srow) * 16;   // swizzled source byte offset
  const int wm = (wave >> 1) * 64, wn = (wave & 1) * 64;
  const int lrow = lane & 15;
  const int rsw = lrow & 7;
  const int kgb = lane >> 4;             // 0..3

  for (int k0 = 0; k0 < K; k0 += 64) {
    __syncthreads();
    for (int i = 0; i < 4; ++i) {
      int chunk = wave * 4 + i;          // 1KB = 8 rows x 128B
      int row = chunk * 8 + srow;
      gl_lds16((const char*)(A + (long)row * lda + k0) + soff, (char*)As + chunk * 1024);
      gl_lds16((const char*)(B + (long)row * ldb + k0) + soff, (char*)Bs + chunk * 1024);
    }
    __syncthreads();
#pragma unroll
    for (int ks = 0; ks < 2; ++ks) {
      bf16x8 af[4], bfr[4];
      const int off = ((ks * 4 + kgb) ^ rsw) * 8;  // shorts
#pragma unroll
      for (int t = 0; t < 4; ++t) {
        af[t]  = *(const bf16x8*)&As[(wm + t * 16 + lrow) * 64 + off];
        bfr[t] = *(const bf16x8*)&Bs[(wn + t * 16 + lrow) * 64 + off];
      }
#pragma unroll
      for (int mt = 0; mt < 4; ++mt)
#pragma unroll
        for (int nt = 0; nt < 4; ++nt)
          acc[mt][nt] = __builtin_amdgcn_mfma_f32_16x16x32_bf16(af[mt], bfr[nt], acc[mt][nt], 0, 0, 0);
    }
  }
}

// epilogue index helpers (C/D layout: col=lane&15, row=(lane>>4)*4+reg)
#define EPILOG_SETUP                                        \
  const int lane = threadIdx.x & 63, wave = threadIdx.x >> 6; \
  const int wm = (wave >> 1) * 64, wn = (wave & 1) * 64;     \
  const int lcol = lane & 15, lrb = (lane >> 4) * 4;

// ---------------- prep: weight transpose + bias pack + stats zero ----------
__global__ void prep_kernel(const float* __restrict__ wq, const float* __restrict__ wk,
                            const float* __restrict__ wv, const float* __restrict__ wo,
                            const float* __restrict__ bq, const float* __restrict__ bk,
                            const float* __restrict__ bv,
                            unsigned short* __restrict__ wqkvT,
                            unsigned short* __restrict__ woT,
                            float* __restrict__ bias, float* __restrict__ stats) {
  long id = (long)blockIdx.x * 256 + threadIdx.x;
  if (id < 786432) {                       // wqkvT[n][k]
    long n = id >> 9, k = id & 511;
    const float* w = (n < 512) ? wq : (n < 1024 ? wk : wv);
    wqkvT[id] = f2bf(w[k * 512 + (n & 511)]);
  } else if (id < 786432 + 262144) {       // woT[n][k]
    long j = id - 786432, n = j >> 9, k = j & 511;
    woT[j] = f2bf(wo[k * 512 + n]);
  } else if (id < 786432 + 262144 + 1536) {
    long j = id - 786432 - 262144;
    bias[j] = (j < 512) ? bq[j] : (j < 1024 ? bk[j - 512] : bv[j - 1024]);
  } else if (id < 786432 + 262144 + 1536 + 256) {
    stats[id - 786432 - 262144 - 1536] = 0.f;
  }
}

// ---------------- GroupNorm pass 1: coalesced partial sums -----------------
__global__ __launch_bounds__(256) void gn_stats(const float* __restrict__ x,
                                                float* __restrict__ stats) {
  const int b = blockIdx.x >> 5, slab = blockIdx.x & 31;
  const float* xp = x + (long)b * 4096 * 512 + (long)slab * 128 * 512;
  const int tid = threadIdx.x;
  float s = 0.f, s2 = 0.f;
  for (int it = 0; it < 64; ++it) {
    int i = it * 256 + tid;                // float4 index; channel = tid&127 fixed
    float4 v = *(const float4*)(xp + (long)i * 4);
    s += v.x + v.y + v.z + v.w;
    s2 += v.x * v.x + v.y * v.y + v.z * v.z + v.w * v.w;
  }
  s += __shfl_xor(s, 1); s += __shfl_xor(s, 2);
  s2 += __shfl_xor(s2, 1); s2 += __shfl_xor(s2, 2);
  if ((tid & 3) == 0) {
    int g = (tid & 127) >> 2;
    atomicAdd(&stats[(b * 32 + g) * 2], s);
    atomicAdd(&stats[(b * 32 + g) * 2 + 1], s2);
  }
}

// ---------------- GroupNorm pass 2: normalize -> bf16, coalesced -----------
__global__ __launch_bounds__(256) void gn_apply(const float* __restrict__ x,
                                                const float* __restrict__ stats,
                                                const float* __restrict__ gamma,
                                                const float* __restrict__ beta,
                                                unsigned short* __restrict__ xn) {
  long id = (long)blockIdx.x * 256 + threadIdx.x;   // float4 id, 2097152 total
  long a = id * 4;
  int b = (int)(id >> 19);
  int ch = (int)(a & 511);
  int g = ch >> 4;
  float s = stats[(b * 32 + g) * 2], s2 = stats[(b * 32 + g) * 2 + 1];
  float mean = s * (1.f / 65536.f);
  float rinv = rsqrtf(s2 * (1.f / 65536.f) - mean * mean + 1e-6f);
  float4 v = *(const float4*)(x + a);
  float4 gm = *(const float4*)(gamma + ch);
  float4 bt = *(const float4*)(beta + ch);
  ushort4 o;
  o.x = f2bf((v.x - mean) * rinv * gm.x + bt.x);
  o.y = f2bf((v.y - mean) * rinv * gm.y + bt.y);
  o.z = f2bf((v.z - mean) * rinv * gm.z + bt.z);
  o.w = f2bf((v.w - mean) * rinv * gm.w + bt.w);
  *(ushort4*)(xn + a) = o;
}

// ---------------- QKV gemm: xn[16384x512] * wqkvT[1536x512]^T --------------
__global__ __launch_bounds__(256) void qkv_kernel(
    const unsigned short* __restrict__ xn, const unsigned short* __restrict__ wqkvT,
    const float* __restrict__ bias, unsigned short* __restrict__ q,
    unsigned short* __restrict__ kk, unsigned short* __restrict__ vv) {
  __shared__ unsigned short As[128 * 64], Bs[128 * 64];
  f32x4 acc[4][4] = {};
  const long tm = (long)blockIdx.x * 128, tn = (long)blockIdx.y * 128;
  gemm_tile(xn + tm * 512, 512, wqkvT + tn * 512, 512, 512, As, Bs, acc);
  EPILOG_SETUP
#pragma unroll
  for (int mt = 0; mt < 4; ++mt)
#pragma unroll
    for (int nt = 0; nt < 4; ++nt)
#pragma unroll
      for (int r = 0; r < 4; ++r) {
        long m = tm + wm + mt * 16 + lrb + r;
        long n = tn + wn + nt * 16 + lcol;
        float v = acc[mt][nt][r] + bias[n];
        if (n < 512)       q[m * 512 + n] = f2bf(v * SOFTMAX_SCALE);  // fold scale
        else if (n < 1024) kk[m * 512 + (n - 512)] = f2bf(v);
        else               vv[m * 512 + (n - 1024)] = f2bf(v);
      }
}

// ---------------- v [b*4096+j][c] -> vT [b*512+c][j], 64x64 LDS tiles ------
__global__ __launch_bounds__(256) void transpose_v(const unsigned short* __restrict__ v,
                                                   unsigned short* __restrict__ vT) {
  const int b = blockIdx.z;
  const long j0 = (long)blockIdx.x * 64, c0 = (long)blockIdx.y * 64;
  __shared__ unsigned short t[64][72];
  const int tc = (threadIdx.x & 15) * 4, tr = threadIdx.x >> 4;  // tr 0..15
  for (int rr = 0; rr < 64; rr += 16) {
    ushort4 u = *(const ushort4*)&v[((long)b * 4096 + j0 + tr + rr) * 512 + c0 + tc];
    t[tr + rr][tc] = u.x; t[tr + rr][tc + 1] = u.y;
    t[tr + rr][tc + 2] = u.z; t[tr + rr][tc + 3] = u.w;
  }
  __syncthreads();
  for (int rr = 0; rr < 64; rr += 16) {
    int c = tr + rr;
    ushort4 o;
    o.x = t[tc + 0][c]; o.y = t[tc + 1][c]; o.z = t[tc + 2][c]; o.w = t[tc + 3][c];
    *(ushort4*)&vT[((long)b * 512 + c0 + c) * 4096 + j0 + tc] = o;
  }
}

// ---------------- QK^T batched: scores bf16 [z][4096][4096] ----------------
__global__ __launch_bounds__(256) void qkt_kernel(
    const unsigned short* __restrict__ q, const unsigned short* __restrict__ kk,
    unsigned short* __restrict__ probs, int b0) {
  __shared__ unsigned short As[128 * 64], Bs[128 * 64];
  f32x4 acc[4][4] = {};
  const int z = blockIdx.z;
  const long tm = (long)blockIdx.x * 128, tn = (long)blockIdx.y * 128;
  const long bb = (long)(b0 + z) * 4096 * 512;
  gemm_tile(q + bb + tm * 512, 512, kk + bb + tn * 512, 512, 512, As, Bs, acc);
  EPILOG_SETUP
  unsigned short* out = probs + (long)z * 4096 * 4096;
#pragma unroll
  for (int mt = 0; mt < 4; ++mt)
#pragma unroll
    for (int nt = 0; nt < 4; ++nt)
#pragma unroll
      for (int r = 0; r < 4; ++r) {
        long m = tm + wm + mt * 16 + lrb + r;
        long n = tn + wn + nt * 16 + lcol;
        out[m * 4096 + n] = f2bf(acc[mt][nt][r]);
      }
}

// ---------------- row softmax on bf16, in place ----------------------------
__global__ __launch_bounds__(256) void softmax_kernel(unsigned short* __restrict__ probs) {
  const long r = blockIdx.x;
  unsigned short* row = probs + r * 4096;
  const int tid = threadIdx.x;
  u16x8 a = *(const u16x8*)(row + tid * 8);
  u16x8 b = *(const u16x8*)(row + 2048 + tid * 8);
  float v[16];
  float mx = -1e30f;
#pragma unroll
  for (int j = 0; j < 8; ++j) {
    v[j] = bf2f(a[j]); v[8 + j] = bf2f(b[j]);
    mx = fmaxf(mx, fmaxf(v[j], v[8 + j]));
  }
  for (int o = 32; o; o >>= 1) mx = fmaxf(mx, __shfl_xor(mx, o));
  __shared__ float redm[4], reds[4];
  int wave = tid >> 6, lane = tid & 63;
  if (lane == 0) redm[wave] = mx;
  __syncthreads();
  mx = fmaxf(fmaxf(redm[0], redm[1]), fmaxf(redm[2], redm[3]));
  float sum = 0.f;
#pragma unroll
  for (int j = 0; j < 16; ++j) { v[j] = __expf(v[j] - mx); sum += v[j]; }
  for (int o = 32; o; o >>= 1) sum += __shfl_xor(sum, o);
  if (lane == 0) reds[wave] = sum;
  __syncthreads();
  sum = reds[0] + reds[1] + reds[2] + reds[3];
  float inv = 1.f / sum;
#pragma unroll
  for (int j = 0; j < 8; ++j) {
    a[j] = f2bf(v[j] * inv); b[j] = f2bf(v[8 + j] * inv);
  }
  *(u16x8*)(row + tid * 8) = a;
  *(u16x8*)(row + 2048 + tid * 8) = b;
}

// ---------------- PV with split-K=2: part[s][zb][4096][512] fp32 -----------
__global__ __launch_bounds__(256) void pv_kernel(
    const unsigned short* __restrict__ probs, const unsigned short* __restrict__ vT,
    float* __restrict__ part, int b0, int nb) {
  __shared__ unsigned short As[128 * 64], Bs[128 * 64];
  f32x4 acc[4][4] = {};
  const int zb = blockIdx.z >> 1, s = blockIdx.z & 1;
  const long tm = (long)blockIdx.x * 128, tn = (long)blockIdx.y * 128;
  gemm_tile(probs + (long)zb * 4096 * 4096 + tm * 4096 + s * 2048, 4096,
            vT + (long)(b0 + zb) * 512 * 4096 + tn * 4096 + s * 2048, 4096,
            2048, As, Bs, acc);
  EPILOG_SETUP
  float* out = part + (long)s * nb * 4096 * 512 + (long)zb * 4096 * 512;
#pragma unroll
  for (int mt = 0; mt < 4; ++mt)
#pragma unroll
    for (int nt = 0; nt < 4; ++nt)
#pragma unroll
      for (int r = 0; r < 4; ++r) {
        long m = tm + wm + mt * 16 + lrb + r;
        long n = tn + wn + nt * 16 + lcol;
        out[m * 512 + n] = acc[mt][nt][r];
      }
}

// ---------------- reduce split-K partials -> attn bf16 ---------------------
__global__ __launch_bounds__(256) void reduce_kernel(const float* __restrict__ part,
                                                     unsigned short* __restrict__ attn,
                                                     long elems) {
  long id = (long)blockIdx.x * 256 + threadIdx.x;
  long a = id * 4;
  float4 p0 = *(const float4*)(part + a);
  float4 p1 = *(const float4*)(part + elems + a);
  ushort4 o;
  o.x = f2bf(p0.x + p1.x); o.y = f2bf(p0.y + p1.y);
  o.z = f2bf(p0.z + p1.z); o.w = f2bf(p0.w + p1.w);
  *(ushort4*)(attn + a) = o;
}

// ---------------- out projection + bias + residual -------------------------
__global__ __launch_bounds__(256) void proj_kernel(
    const unsigned short* __restrict__ attn, const unsigned short* __restrict__ woT,
    const float* __restrict__ bo, const float* __restrict__ x,
    float* __restrict__ out) {
  __shared__ unsigned short As[128 * 64], Bs[128 * 64];
  f32x4 acc[4][4] = {};
  const long tm = (long)blockIdx.x * 128, tn = (long)blockIdx.y * 128;
  gemm_tile(attn + tm * 512, 512, woT + tn * 512, 512, 512, As, Bs, acc);
  EPILOG_SETUP
#pragma unroll
  for (int mt = 0; mt < 4; ++mt)
#pragma unroll
    for (int nt = 0; nt < 4; ++nt)
#pragma unroll
      for (int r = 0; r < 4; ++r) {
        long m = tm + wm + mt * 16 + lrb + r;
        long n = tn + wn + nt * 16 + lcol;
        out[m * 512 + n] = acc[mt][nt][r] + bo[n] + x[m * 512 + n];
      }
}

extern "C" void kernel_launch(void* const* d_in, const int* in_sizes, int n_in,
                              void* d_out, int out_size, void* d_ws, size_t ws_size,
                              hipStream_t stream) {
  const float* x     = (const float*)d_in[0];
  const float* gamma = (const float*)d_in[1];
  const float* beta  = (const float*)d_in[2];
  const float* wq    = (const float*)d_in[3];
  const float* bq    = (const float*)d_in[4];
  const float* wk    = (const float*)d_in[5];
  const float* bk    = (const float*)d_in[6];
  const float* wv    = (const float*)d_in[7];
  const float* bv    = (const float*)d_in[8];
  const float* wo    = (const float*)d_in[9];
  const float* bo    = (const float*)d_in[10];

  char* p = (char*)d_ws;
  auto take = [&](size_t bytes) { char* r = p; p += (bytes + 255) & ~(size_t)255; return r; };
  const long NTOK = 16384, C = 512, HW = 4096;
  unsigned short* xn    = (unsigned short*)take(NTOK * C * 2);
  unsigned short* q     = (unsigned short*)take(NTOK * C * 2);
  unsigned short* kbuf  = (unsigned short*)take(NTOK * C * 2);
  unsigned short* vbuf  = (unsigned short*)take(NTOK * C * 2);
  unsigned short* vT    = (unsigned short*)take(NTOK * C * 2);
  unsigned short* attn  = (unsigned short*)take(NTOK * C * 2);
  unsigned short* wqkvT = (unsigned short*)take(1536l * 512 * 2);
  unsigned short* woT   = (unsigned short*)take(512l * 512 * 2);
  float* bias           = (float*)take(1536 * 4);
  float* stats          = (float*)take(256 * 4);

  size_t fixed = (size_t)(p - (char*)d_ws);
  // full-batched needs probs 4x(4096^2x2) + part 2x4x(4096x512x4)
  size_t need_full = fixed + 4ul * HW * HW * 2 + 2ul * 4 * HW * C * 4 + 1024;
  int NB = (ws_size >= need_full) ? 4 : 1;
  unsigned short* probs = (unsigned short*)take((size_t)NB * HW * HW * 2);
  float* part           = (float*)take(2ul * NB * HW * C * 4);

  prep_kernel<<<4103, 256, 0, stream>>>(wq, wk, wv, wo, bq, bk, bv, wqkvT, woT, bias, stats);
  gn_stats<<<128, 256, 0, stream>>>(x, stats);
  gn_apply<<<8192, 256, 0, stream>>>(x, stats, gamma, beta, xn);

  qkv_kernel<<<dim3(128, 12), 256, 0, stream>>>(xn, wqkvT, bias, q, kbuf, vbuf);
  transpose_v<<<dim3(64, 8, 4), 256, 0, stream>>>(vbuf, vT);

  for (int b0 = 0; b0 < 4; b0 += NB) {
    qkt_kernel<<<dim3(32, 32, NB), 256, 0, stream>>>(q, kbuf, probs, b0);
    softmax_kernel<<<NB * 4096, 256, 0, stream>>>(probs);
    pv_kernel<<<dim3(32, 4, 2 * NB), 256, 0, stream>>>(probs, vT, part, b0, NB);
    reduce_kernel<<<NB * 2048, 256, 0, stream>>>(part, attn + (long)b0 * HW * C,
                                                 (long)NB * HW * C);
  }

  proj_kernel<<<dim3(128, 4), 256, 0, stream>>>(attn, woT, bo, x, (float*)d_out);
}